// Round 11
// baseline (2319.392 us; speedup 1.0000x reference)
//
#include <hip/hip_runtime.h>

// RATSQL relation-aware transformer layer, MI355X.
// Round 11: d_out is FP32 (R10 spike probe: bf16 spike invisible, absmax ==
// all-zeros value 4.6875). All inputs fp32, rel/mask int32, REL=100 DH=32 NH=8
// (R7 battery). R2's tiled pipeline == naive pipeline bit-identically (R2 vs
// R4), so the optimized structure is used: tiled 64x64 GEMM, KV transposed to
// (B,NH,DH,L), LDS-staged Ek/Ev attention, shuffle reductions. Final LN writes
// fp32 to d_out.

typedef unsigned short bf16;

// ---------- fp32 copy ----------
__global__ void cp_k(const float* __restrict__ in, float* __restrict__ out, int n) {
  int i = blockIdx.x * blockDim.x + threadIdx.x;
  int st = gridDim.x * blockDim.x;
  for (; i < n; i += st) out[i] = in[i];
}

// ---------- tiled GEMM: C = act(A(MxK) @ B(KxN) + bias), all fp32 ----------
// kvmode=1: write C transposed to (B,NH,DH,L) layout for k/v.
__global__ __launch_bounds__(256) void gemm_k(
    const float* __restrict__ A, const float* __restrict__ Bw, size_t beoff,
    const float* __restrict__ bias, size_t boff, float* __restrict__ C,
    int M, int N, int K, int kvmode, int do_relu)
{
  __shared__ float As[16][68];
  __shared__ float Bs[16][68];
  int tid = threadIdx.x;
  int m0 = blockIdx.y * 64, n0 = blockIdx.x * 64;
  int tx = tid & 15, ty = tid >> 4;
  int arow = tid >> 2, acol = (tid & 3) << 2;
  int brow = tid >> 4, bcol = (tid & 15) << 2;
  float acc[4][4] = {{0.f}};
  for (int k0 = 0; k0 < K; k0 += 16) {
    float4 a4 = *(const float4*)(A + (size_t)(m0 + arow) * K + k0 + acol);
    As[acol + 0][arow] = a4.x;
    As[acol + 1][arow] = a4.y;
    As[acol + 2][arow] = a4.z;
    As[acol + 3][arow] = a4.w;
    float4 b4 = *(const float4*)(Bw + beoff + (size_t)(k0 + brow) * N + n0 + bcol);
    Bs[brow][bcol + 0] = b4.x;
    Bs[brow][bcol + 1] = b4.y;
    Bs[brow][bcol + 2] = b4.z;
    Bs[brow][bcol + 3] = b4.w;
    __syncthreads();
#pragma unroll
    for (int kk = 0; kk < 16; ++kk) {
      float a[4], b[4];
#pragma unroll
      for (int r = 0; r < 4; ++r) a[r] = As[kk][ty * 4 + r];
#pragma unroll
      for (int c = 0; c < 4; ++c) b[c] = Bs[kk][tx * 4 + c];
#pragma unroll
      for (int r = 0; r < 4; ++r)
#pragma unroll
        for (int c = 0; c < 4; ++c)
          acc[r][c] += a[r] * b[c];
    }
    __syncthreads();
  }
  float bv[4] = {0.f, 0.f, 0.f, 0.f};
  if (bias) {
#pragma unroll
    for (int c = 0; c < 4; ++c) bv[c] = bias[boff + n0 + tx * 4 + c];
  }
#pragma unroll
  for (int r = 0; r < 4; ++r) {
    int m = m0 + ty * 4 + r;
#pragma unroll
    for (int c = 0; c < 4; ++c) {
      int n = n0 + tx * 4 + c;
      float v = acc[r][c] + bv[c];
      if (do_relu) v = fmaxf(v, 0.f);
      if (!kvmode) {
        C[(size_t)m * N + n] = v;
      } else {
        int b = m >> 10, i = m & 1023, h = n >> 5, d = n & 31;
        C[(size_t)((((b << 3) + h) << 5) + d) * 1024 + i] = v;
      }
    }
  }
}

// ---------- fused relation-aware attention: one block per (b,h,i) ----------
__global__ __launch_bounds__(256) void attn_k(
    const float* __restrict__ q, const float* __restrict__ kT,
    const float* __restrict__ vT, const float* __restrict__ Ek,
    const float* __restrict__ Ev, const int* __restrict__ rel,
    const int* __restrict__ msk, float* __restrict__ out)
{
  __shared__ float qs[32];
  __shared__ float Eks[100 * 33];  // stride 33: bank=(rel+d)%32
  __shared__ float Evs[100 * 33];
  __shared__ float red[256];
  int tid = threadIdx.x;
  int i = blockIdx.x & 1023;
  int h = (blockIdx.x >> 10) & 7;
  int b = blockIdx.x >> 13;
  for (int idx = tid; idx < 100 * 32; idx += 256) {
    int r = idx >> 5, d = idx & 31;
    Eks[r * 33 + d] = Ek[idx];
    Evs[r * 33 + d] = Ev[idx];
  }
  if (tid < 32)
    qs[tid] = q[(((size_t)(b * 1024 + i) * 8 + h) << 5) + tid] * 0.17677669529663687f; // 1/sqrt(32)
  __syncthreads();
  const float* kTb = kT + (size_t)((b * 8 + h) * 32) * 1024;  // [d][j]
  const float* vTb = vT + (size_t)((b * 8 + h) * 32) * 1024;
  size_t rowoff = (size_t)(b * 1024 + i) * 1024;
  float sc[4];
  int rl[4];
  float mx = -3.0e38f;
#pragma unroll
  for (int s = 0; s < 4; ++s) {
    int j = tid + s * 256;
    int rv = rel[rowoff + j];
    rl[s] = rv;
    const float* ep = Eks + rv * 33;
    float a = 0.f;
#pragma unroll
    for (int d = 0; d < 32; ++d)
      a += qs[d] * (kTb[d * 1024 + j] + ep[d]);
    if (msk[rowoff + j]) a = -1e20f;  // fp32 absorption == additive -1e20
    sc[s] = a;
    mx = fmaxf(mx, a);
  }
  red[tid] = mx;
  __syncthreads();
  for (int off = 128; off > 0; off >>= 1) {
    if (tid < off) red[tid] = fmaxf(red[tid], red[tid + off]);
    __syncthreads();
  }
  float gmax = red[0];
  __syncthreads();
  float ls = 0.f;
#pragma unroll
  for (int s = 0; s < 4; ++s) { sc[s] = __expf(sc[s] - gmax); ls += sc[s]; }
  red[tid] = ls;
  __syncthreads();
  for (int off = 128; off > 0; off >>= 1) {
    if (tid < off) red[tid] += red[tid + off];
    __syncthreads();
  }
  float ginv = 1.f / red[0];
  float oacc[32];
#pragma unroll
  for (int d = 0; d < 32; ++d) oacc[d] = 0.f;
#pragma unroll
  for (int s = 0; s < 4; ++s) {
    int j = tid + s * 256;
    float p = sc[s];
    const float* ep = Evs + rl[s] * 33;
#pragma unroll
    for (int d = 0; d < 32; ++d)
      oacc[d] += p * (vTb[d * 1024 + j] + ep[d]);
  }
#pragma unroll
  for (int d = 0; d < 32; ++d) {
    float v = oacc[d];
#pragma unroll
    for (int off = 32; off > 0; off >>= 1) v += __shfl_xor(v, off, 64);
    oacc[d] = v;
  }
  __syncthreads();
  int lane = tid & 63, w = tid >> 6;
#pragma unroll
  for (int d = 0; d < 32; ++d)
    if (lane == d) red[w * 32 + d] = oacc[d];
  __syncthreads();
  if (tid < 32) {
    float r = red[tid] + red[32 + tid] + red[64 + tid] + red[96 + tid];
    out[(((size_t)(b * 1024 + i) * 8 + h) << 5) + tid] = r * ginv;
  }
}

// ---------- residual + LayerNorm (block per row of 256) ----------
__global__ __launch_bounds__(256) void ln_k(
    const float* __restrict__ x, const float* __restrict__ o,
    const float* __restrict__ g, const float* __restrict__ bta, size_t eoff,
    float* __restrict__ xo, float* __restrict__ fout)
{
  __shared__ float red[256];
  int row = blockIdx.x, t = threadIdx.x;
  size_t idx = (size_t)row * 256 + t;
  float r = x[idx] + o[idx];
  red[t] = r;
  __syncthreads();
  for (int off = 128; off > 0; off >>= 1) {
    if (t < off) red[t] += red[t + off];
    __syncthreads();
  }
  float mean = red[0] * (1.f / 256.f);
  __syncthreads();
  float dv = r - mean;
  red[t] = dv * dv;
  __syncthreads();
  for (int off = 128; off > 0; off >>= 1) {
    if (t < off) red[t] += red[t + off];
    __syncthreads();
  }
  float var = red[0] * (1.f / 256.f);
  float val = dv * rsqrtf(var + 1e-5f) * g[eoff + t] + bta[eoff + t];
  xo[idx] = val;
  if (fout) fout[idx] = val;
}

extern "C" void kernel_launch(void* const* d_in, const int* in_sizes, int n_in,
                              void* d_out, int out_size, void* d_ws, size_t ws_size,
                              hipStream_t stream) {
  const float* inp  = (const float*)d_in[0];
  const float* Wq   = (const float*)d_in[1];
  const float* Wk   = (const float*)d_in[2];
  const float* Wv   = (const float*)d_in[3];
  const float* Wo   = (const float*)d_in[4];
  const float* bo   = (const float*)d_in[5];
  const float* W1   = (const float*)d_in[6];
  const float* b1   = (const float*)d_in[7];
  const float* W2   = (const float*)d_in[8];
  const float* b2   = (const float*)d_in[9];
  const float* ln1g = (const float*)d_in[10];
  const float* ln1b = (const float*)d_in[11];
  const float* ln2g = (const float*)d_in[12];
  const float* ln2b = (const float*)d_in[13];
  const float* Ek   = (const float*)d_in[14];
  const float* Ev   = (const float*)d_in[15];
  const int*   rel  = (const int*)d_in[16];
  const int*   msk  = (const int*)d_in[17];

  const size_t SZ = 524288;  // 2048*256
  float* x    = (float*)d_ws;
  float* q    = x + SZ;                 // region R: q,kT,vT,attn = 8 MB
  float* kT   = q + SZ;
  float* vT   = kT + SZ;
  float* attn = vT + SZ;
  float* tmp  = attn + SZ;              // 2 MB
  float* ffh  = q;                      // 8 MB alias over R (dead during FF)

  cp_k<<<512, 256, 0, stream>>>(inp, x, (int)SZ);

  dim3 blk(256);
  for (int l = 0; l < 2; ++l) {
    size_t o_w  = (size_t)l * 65536;
    size_t o_b  = (size_t)l * 256;
    size_t o_w1 = (size_t)l * 262144;
    size_t o_b1 = (size_t)l * 1024;

    gemm_k<<<dim3(4, 32), blk, 0, stream>>>(x, Wq, o_w, nullptr, 0, q,
                                            2048, 256, 256, 0, 0);
    gemm_k<<<dim3(4, 32), blk, 0, stream>>>(x, Wk, o_w, nullptr, 0, kT,
                                            2048, 256, 256, 1, 0);
    gemm_k<<<dim3(4, 32), blk, 0, stream>>>(x, Wv, o_w, nullptr, 0, vT,
                                            2048, 256, 256, 1, 0);

    attn_k<<<16384, blk, 0, stream>>>(q, kT, vT, Ek, Ev, rel, msk, attn);

    gemm_k<<<dim3(4, 32), blk, 0, stream>>>(attn, Wo, o_w, bo, o_b, tmp,
                                            2048, 256, 256, 0, 0);
    ln_k<<<2048, blk, 0, stream>>>(x, tmp, ln1g, ln1b, o_b, x, nullptr);

    gemm_k<<<dim3(16, 32), blk, 0, stream>>>(x, W1, o_w1, b1, o_b1, ffh,
                                             2048, 1024, 256, 0, 1);
    gemm_k<<<dim3(4, 32), blk, 0, stream>>>(ffh, W2, o_w1, b2, o_b, tmp,
                                            2048, 256, 1024, 0, 0);
    ln_k<<<2048, blk, 0, stream>>>(x, tmp, ln2g, ln2b, o_b, x,
                                   (l == 1) ? (float*)d_out : nullptr);
  }
}

// Round 12
// 804.849 us; speedup vs baseline: 2.8818x; 2.8818x over previous
//
#include <hip/hip_runtime.h>

// RATSQL relation-aware transformer layer, MI355X.
// Round 12: attention restructure. R11 baseline 2319us, attn_k = 2x997us,
// latency-bound (VALU 14%, occ 24%, 5.4e7 LDS conflicts from per-j Ek gather,
// 27.6KB LDS staging repeated 16384x). Algebraic fix:
//   score_ij = qk_ij + qEk[i, rel_ij],  qEk[i,r] = (q_i/S)·Ek[r]  (per-block)
//   out_i    = sum_j p_ij v_j + sum_r w[i,r] Ev[r],  w = p-histogram over rel
// Block = 4 i's of one (b,h): k/v L2 traffic /4, Ek staging amortized, no
// random-lane gathers in the j-loop. LDS 24.8KB -> 6 blocks/CU.

typedef unsigned short bf16;

__global__ void cp_k(const float* __restrict__ in, float* __restrict__ out, int n) {
  int i = blockIdx.x * blockDim.x + threadIdx.x;
  int st = gridDim.x * blockDim.x;
  for (; i < n; i += st) out[i] = in[i];
}

// ---------- tiled GEMM: C = act(A(MxK) @ B(KxN) + bias), all fp32 ----------
// kvmode=1: write C transposed to (B,NH,DH,L) layout for k/v.
__global__ __launch_bounds__(256) void gemm_k(
    const float* __restrict__ A, const float* __restrict__ Bw, size_t beoff,
    const float* __restrict__ bias, size_t boff, float* __restrict__ C,
    int M, int N, int K, int kvmode, int do_relu)
{
  __shared__ float As[16][68];
  __shared__ float Bs[16][68];
  int tid = threadIdx.x;
  int m0 = blockIdx.y * 64, n0 = blockIdx.x * 64;
  int tx = tid & 15, ty = tid >> 4;
  int arow = tid >> 2, acol = (tid & 3) << 2;
  int brow = tid >> 4, bcol = (tid & 15) << 2;
  float acc[4][4] = {{0.f}};
  for (int k0 = 0; k0 < K; k0 += 16) {
    float4 a4 = *(const float4*)(A + (size_t)(m0 + arow) * K + k0 + acol);
    As[acol + 0][arow] = a4.x;
    As[acol + 1][arow] = a4.y;
    As[acol + 2][arow] = a4.z;
    As[acol + 3][arow] = a4.w;
    float4 b4 = *(const float4*)(Bw + beoff + (size_t)(k0 + brow) * N + n0 + bcol);
    Bs[brow][bcol + 0] = b4.x;
    Bs[brow][bcol + 1] = b4.y;
    Bs[brow][bcol + 2] = b4.z;
    Bs[brow][bcol + 3] = b4.w;
    __syncthreads();
#pragma unroll
    for (int kk = 0; kk < 16; ++kk) {
      float a[4], b[4];
#pragma unroll
      for (int r = 0; r < 4; ++r) a[r] = As[kk][ty * 4 + r];
#pragma unroll
      for (int c = 0; c < 4; ++c) b[c] = Bs[kk][tx * 4 + c];
#pragma unroll
      for (int r = 0; r < 4; ++r)
#pragma unroll
        for (int c = 0; c < 4; ++c)
          acc[r][c] += a[r] * b[c];
    }
    __syncthreads();
  }
  float bv[4] = {0.f, 0.f, 0.f, 0.f};
  if (bias) {
#pragma unroll
    for (int c = 0; c < 4; ++c) bv[c] = bias[boff + n0 + tx * 4 + c];
  }
#pragma unroll
  for (int r = 0; r < 4; ++r) {
    int m = m0 + ty * 4 + r;
#pragma unroll
    for (int c = 0; c < 4; ++c) {
      int n = n0 + tx * 4 + c;
      float v = acc[r][c] + bv[c];
      if (do_relu) v = fmaxf(v, 0.f);
      if (!kvmode) {
        C[(size_t)m * N + n] = v;
      } else {
        int b = m >> 10, i = m & 1023, h = n >> 5, d = n & 31;
        C[(size_t)((((b << 3) + h) << 5) + d) * 1024 + i] = v;
      }
    }
  }
}

// ---------- relation-aware attention v2: block = (b, h, 4 i's) ----------
__global__ __launch_bounds__(256) void attn2_k(
    const float* __restrict__ q, const float* __restrict__ kT,
    const float* __restrict__ vT, const float* __restrict__ Ek,
    const float* __restrict__ Ev, const int* __restrict__ rel,
    const int* __restrict__ msk, float* __restrict__ out)
{
  __shared__ float uni[4096];      // phase A: Ek staged (r*33+d); phase B: ps[4][1024]
  __shared__ float qs[128];        // [i][d], pre-scaled by 1/sqrt(32)
  __shared__ float qek[4 * 101];   // qEk[i][r]
  __shared__ float wbin[4 * 101];  // p-histogram w[i][r]
  __shared__ float red4[1024];     // packed 4-way reductions
  __shared__ float ovec[128];      // o[i][d] after butterfly

  int tid = threadIdx.x;
  int tile = blockIdx.x & 255;
  int h = (blockIdx.x >> 8) & 7;
  int b = blockIdx.x >> 11;
  int i0 = tile << 2;

  // ---- stage Ek (padded 33) + q rows ----
  for (int idx = tid; idx < 3200; idx += 256) {
    int r = idx >> 5, d = idx & 31;
    uni[r * 33 + d] = Ek[idx];
  }
  if (tid < 128) {
    int i = tid >> 5, d = tid & 31;
    qs[tid] = q[(((size_t)(b * 1024 + i0 + i) * 8 + h) << 5) + d] * 0.17677669529663687f;
  }
  __syncthreads();

  // ---- qek[i][r] = qs[i]·Ek[r]; init histogram ----
  for (int p = tid; p < 400; p += 256) {
    int i = p / 100, r = p - i * 100;
    float s = 0.f;
#pragma unroll
    for (int d = 0; d < 32; ++d) s += qs[i * 32 + d] * uni[r * 33 + d];
    qek[i * 101 + r] = s;
    wbin[i * 101 + r] = 0.f;
  }
  __syncthreads();  // uni free for ps after this

  const float* kTb = kT + ((size_t)(b * 8 + h) << 15);  // [d][j]
  const float* vTb = vT + ((size_t)(b * 8 + h) << 15);

  // ---- scores: thread covers j = tid + 256s, all 4 i's ----
  float sc[4][4];
  int rl[4][4];
  float mx[4] = {-3.0e38f, -3.0e38f, -3.0e38f, -3.0e38f};
#pragma unroll
  for (int s = 0; s < 4; ++s) {
    int j = tid + (s << 8);
    float acc[4] = {0.f, 0.f, 0.f, 0.f};
#pragma unroll
    for (int d = 0; d < 32; ++d) {
      float kv = kTb[(d << 10) + j];
#pragma unroll
      for (int i = 0; i < 4; ++i) acc[i] += qs[i * 32 + d] * kv;
    }
#pragma unroll
    for (int i = 0; i < 4; ++i) {
      size_t ro = ((size_t)(b * 1024 + i0 + i) << 10) + j;
      int rv = rel[ro];
      rl[s][i] = rv;
      float a = acc[i] + qek[i * 101 + rv];
      if (msk[ro]) a = -1e20f;
      sc[s][i] = a;
      mx[i] = fmaxf(mx[i], a);
    }
  }

  // ---- packed 4-way max reduction ----
#pragma unroll
  for (int i = 0; i < 4; ++i) red4[i * 256 + tid] = mx[i];
  __syncthreads();
  for (int off = 128; off > 0; off >>= 1) {
    if (tid < off) {
#pragma unroll
      for (int i = 0; i < 4; ++i)
        red4[i * 256 + tid] = fmaxf(red4[i * 256 + tid], red4[i * 256 + tid + off]);
    }
    __syncthreads();
  }
  float gm[4];
#pragma unroll
  for (int i = 0; i < 4; ++i) gm[i] = red4[i * 256];
  __syncthreads();

  // ---- p = exp(sc - gmax): write ps, histogram, partial sums ----
  float ts[4] = {0.f, 0.f, 0.f, 0.f};
#pragma unroll
  for (int s = 0; s < 4; ++s) {
    int j = tid + (s << 8);
#pragma unroll
    for (int i = 0; i < 4; ++i) {
      float p = __expf(sc[s][i] - gm[i]);
      uni[i * 1024 + j] = p;
      ts[i] += p;
      atomicAdd(&wbin[i * 101 + rl[s][i]], p);
    }
  }
#pragma unroll
  for (int i = 0; i < 4; ++i) red4[i * 256 + tid] = ts[i];
  __syncthreads();
  for (int off = 128; off > 0; off >>= 1) {
    if (tid < off) {
#pragma unroll
      for (int i = 0; i < 4; ++i)
        red4[i * 256 + tid] += red4[i * 256 + tid + off];
    }
    __syncthreads();
  }
  // red4[i*256] = softmax denominator for row i (stays valid below)

  // ---- PV: wave wv handles i = wv; lane covers j = lane + 64s ----
  int wv = tid >> 6, lane = tid & 63;
  float oacc[32];
#pragma unroll
  for (int d = 0; d < 32; ++d) oacc[d] = 0.f;
  for (int s = 0; s < 16; ++s) {
    int j = lane + (s << 6);
    float p = uni[wv * 1024 + j];
#pragma unroll
    for (int d = 0; d < 32; ++d) oacc[d] += p * vTb[(d << 10) + j];
  }
#pragma unroll
  for (int d = 0; d < 32; ++d) {
    float v = oacc[d];
#pragma unroll
    for (int off = 32; off > 0; off >>= 1) v += __shfl_xor(v, off, 64);
    if (lane == d) ovec[wv * 32 + d] = v;
  }
  __syncthreads();

  // ---- Ev term + normalize + write ----
  if (lane < 32) {
    int d = lane;
    float ev = 0.f;
    for (int r = 0; r < 100; ++r)
      ev += wbin[wv * 101 + r] * Ev[(r << 5) + d];
    float ginv = 1.f / red4[wv * 256];
    out[(((size_t)(b * 1024 + i0 + wv) * 8 + h) << 5) + d] =
        (ovec[wv * 32 + d] + ev) * ginv;
  }
}

// ---------- residual + LayerNorm (block per row of 256) ----------
__global__ __launch_bounds__(256) void ln_k(
    const float* __restrict__ x, const float* __restrict__ o,
    const float* __restrict__ g, const float* __restrict__ bta, size_t eoff,
    float* __restrict__ xo, float* __restrict__ fout)
{
  __shared__ float red[256];
  int row = blockIdx.x, t = threadIdx.x;
  size_t idx = (size_t)row * 256 + t;
  float r = x[idx] + o[idx];
  red[t] = r;
  __syncthreads();
  for (int off = 128; off > 0; off >>= 1) {
    if (t < off) red[t] += red[t + off];
    __syncthreads();
  }
  float mean = red[0] * (1.f / 256.f);
  __syncthreads();
  float dv = r - mean;
  red[t] = dv * dv;
  __syncthreads();
  for (int off = 128; off > 0; off >>= 1) {
    if (t < off) red[t] += red[t + off];
    __syncthreads();
  }
  float var = red[0] * (1.f / 256.f);
  float val = dv * rsqrtf(var + 1e-5f) * g[eoff + t] + bta[eoff + t];
  xo[idx] = val;
  if (fout) fout[idx] = val;
}

extern "C" void kernel_launch(void* const* d_in, const int* in_sizes, int n_in,
                              void* d_out, int out_size, void* d_ws, size_t ws_size,
                              hipStream_t stream) {
  const float* inp  = (const float*)d_in[0];
  const float* Wq   = (const float*)d_in[1];
  const float* Wk   = (const float*)d_in[2];
  const float* Wv   = (const float*)d_in[3];
  const float* Wo   = (const float*)d_in[4];
  const float* bo   = (const float*)d_in[5];
  const float* W1   = (const float*)d_in[6];
  const float* b1   = (const float*)d_in[7];
  const float* W2   = (const float*)d_in[8];
  const float* b2   = (const float*)d_in[9];
  const float* ln1g = (const float*)d_in[10];
  const float* ln1b = (const float*)d_in[11];
  const float* ln2g = (const float*)d_in[12];
  const float* ln2b = (const float*)d_in[13];
  const float* Ek   = (const float*)d_in[14];
  const float* Ev   = (const float*)d_in[15];
  const int*   rel  = (const int*)d_in[16];
  const int*   msk  = (const int*)d_in[17];

  const size_t SZ = 524288;  // 2048*256
  float* x    = (float*)d_ws;
  float* q    = x + SZ;                 // region R: q,kT,vT,attn = 8 MB
  float* kT   = q + SZ;
  float* vT   = kT + SZ;
  float* attn = vT + SZ;
  float* tmp  = attn + SZ;              // 2 MB
  float* ffh  = q;                      // 8 MB alias over R (dead during FF)

  cp_k<<<512, 256, 0, stream>>>(inp, x, (int)SZ);

  dim3 blk(256);
  for (int l = 0; l < 2; ++l) {
    size_t o_w  = (size_t)l * 65536;
    size_t o_b  = (size_t)l * 256;
    size_t o_w1 = (size_t)l * 262144;
    size_t o_b1 = (size_t)l * 1024;

    gemm_k<<<dim3(4, 32), blk, 0, stream>>>(x, Wq, o_w, nullptr, 0, q,
                                            2048, 256, 256, 0, 0);
    gemm_k<<<dim3(4, 32), blk, 0, stream>>>(x, Wk, o_w, nullptr, 0, kT,
                                            2048, 256, 256, 1, 0);
    gemm_k<<<dim3(4, 32), blk, 0, stream>>>(x, Wv, o_w, nullptr, 0, vT,
                                            2048, 256, 256, 1, 0);

    attn2_k<<<4096, blk, 0, stream>>>(q, kT, vT, Ek, Ev, rel, msk, attn);

    gemm_k<<<dim3(4, 32), blk, 0, stream>>>(attn, Wo, o_w, bo, o_b, tmp,
                                            2048, 256, 256, 0, 0);
    ln_k<<<2048, blk, 0, stream>>>(x, tmp, ln1g, ln1b, o_b, x, nullptr);

    gemm_k<<<dim3(16, 32), blk, 0, stream>>>(x, W1, o_w1, b1, o_b1, ffh,
                                             2048, 1024, 256, 0, 1);
    gemm_k<<<dim3(4, 32), blk, 0, stream>>>(ffh, W2, o_w1, b2, o_b, tmp,
                                            2048, 256, 1024, 0, 0);
    ln_k<<<2048, blk, 0, stream>>>(x, tmp, ln2g, ln2b, o_b, x,
                                   (l == 1) ? (float*)d_out : nullptr);
  }
}